// Round 6
// baseline (248.440 us; speedup 1.0000x reference)
//
#include <hip/hip_runtime.h>
#include <hip/hip_fp16.h>

// QuantizedLinearWhisper: E2M1 block-32 fake-quant of x and W, then x_q @ W_q^T + bias.
// M=12000 (pad 12032=47*256), K=1280, N=5120. Outputs: out[12000][5120] f32, scale_w[5120][40] f32.
//
// R6: 256x256 GEMM, 4 phases/tile, same-phase fragment use (register-safe), balanced
// region-granular staging (A split by row&64, B by row&32 to match wave read regions),
// 7-phase staging lead, counted vmcnt at each read phase (ledger-derived 12/10/12),
// 4 barriers/tile, setprio on MFMA clusters, XOR chunk swizzle (0 conflicts).

typedef _Float16 f16;
typedef _Float16 f16x8 __attribute__((ext_vector_type(8)));
typedef float f32x4 __attribute__((ext_vector_type(4)));

#define M_ROWS 12000
#define M_PAD  12032
#define N_COLS 5120
#define K_DIM  1280
#define KB     40
#define NT     20
#define NTN    20

#define BAR()   asm volatile("s_barrier" ::: "memory")
#define LGKM0() asm volatile("s_waitcnt lgkmcnt(0)" ::: "memory")
#define VMCNT(N) asm volatile("s_waitcnt vmcnt(%0)" :: "i"(N) : "memory")
#define GLDS(gp, lp) __builtin_amdgcn_global_load_lds( \
    (const __attribute__((address_space(1))) unsigned*)(gp), \
    (__attribute__((address_space(3))) unsigned*)(lp), 16, 0, 0)

// ---- E2M1 nearest-level (strict > boundaries, identical to reference) ----
__device__ __forceinline__ float e2m1_level(float a) {
    float lv;
    if (a > 2.5f)       lv = (a > 3.5f) ? ((a > 5.0f) ? 6.0f : 4.0f) : 3.0f;
    else if (a > 1.25f) lv = (a > 1.75f) ? 2.0f : 1.5f;
    else                lv = (a > 0.75f) ? 1.0f : ((a > 0.25f) ? 0.5f : 0.0f);
    return lv;
}

__global__ __launch_bounds__(256) void quant_x_kernel(const float* __restrict__ x,
                                                      f16* __restrict__ xq) {
    int t = blockIdx.x * blockDim.x + threadIdx.x;
    int row = t / 160;
    int c8  = t % 160;
    f16x8 o;
    if (row < M_ROWS) {
        const float* p = x + (size_t)row * K_DIM + c8 * 8;
        float v[8];
        *(float4*)&v[0] = *(const float4*)p;
        *(float4*)&v[4] = *(const float4*)(p + 4);
        float am = 0.0f;
        #pragma unroll
        for (int i = 0; i < 8; ++i) am = fmaxf(am, fabsf(v[i]));
        am = fmaxf(am, __shfl_xor(am, 1));
        am = fmaxf(am, __shfl_xor(am, 2));
        float scale = fmaxf(am / 6.0f, 1e-12f);
        #pragma unroll
        for (int i = 0; i < 8; ++i) {
            float tq = v[i] / scale;
            float q  = copysignf(e2m1_level(fabsf(tq)), tq) * scale;
            o[i] = (f16)q;
        }
    } else {
        #pragma unroll
        for (int i = 0; i < 8; ++i) o[i] = (f16)0.0f;
    }
    *(f16x8*)(xq + (size_t)row * K_DIM + c8 * 8) = o;
}

__global__ __launch_bounds__(256) void quant_w_kernel(const float* __restrict__ w,
                                                      f16* __restrict__ wq,
                                                      float* __restrict__ scale_out) {
    int t = blockIdx.x * blockDim.x + threadIdx.x;
    int row = t / 160;
    int c8  = t % 160;
    const float* p = w + (size_t)row * K_DIM + c8 * 8;
    float v[8];
    *(float4*)&v[0] = *(const float4*)p;
    *(float4*)&v[4] = *(const float4*)(p + 4);
    float am = 0.0f;
    #pragma unroll
    for (int i = 0; i < 8; ++i) am = fmaxf(am, fabsf(v[i]));
    am = fmaxf(am, __shfl_xor(am, 1));
    am = fmaxf(am, __shfl_xor(am, 2));
    float scale = fmaxf(am / 6.0f, 1e-12f);
    if ((t & 3) == 0) scale_out[row * KB + (c8 >> 2)] = scale;
    f16x8 o;
    #pragma unroll
    for (int i = 0; i < 8; ++i) {
        float tq = v[i] / scale;
        float q  = copysignf(e2m1_level(fabsf(tq)), tq) * scale;
        o[i] = (f16)q;
    }
    *(f16x8*)(wq + (size_t)row * K_DIM + c8 * 8) = o;
}

// ---- GEMM 256x256, BK=64, 512 threads (8 waves 2x4), per-wave 128x64 out ----
// LDS per buffer: A [256 rows][8 chunks of 16B] (32KB) + B same; chunk c of row r
// at slot (c ^ (r&7)); stage pre-swizzles the global source chunk.
// Staged regions match wave read sets: A region h = rows {r: (r>>6)&1 == h}
// (read as Alo/Ahi by both wr groups); B region h = rows {r: (r>>5)&1 == h}.

__device__ __forceinline__ void stage_A(const f16* __restrict__ g, f16* l, int tid, int h) {
    #pragma unroll
    for (int s = 0; s < 2; ++s) {
        int j   = s * 512 + tid;                       // chunk 0..1023
        int rp  = j >> 3;
        int row = (rp & 63) + ((rp >> 6) << 7) + (h << 6);
        int c   = (j & 7) ^ (row & 7);
        GLDS(g + (size_t)row * K_DIM + c * 8, l + (size_t)(row * 8 + (j & 7)) * 8);
    }
}
__device__ __forceinline__ void stage_B(const f16* __restrict__ g, f16* l, int tid, int h) {
    #pragma unroll
    for (int s = 0; s < 2; ++s) {
        int j   = s * 512 + tid;
        int rp  = j >> 3;
        int row = (rp & 31) + ((rp >> 5) << 6) + (h << 5);
        int c   = (j & 7) ^ (row & 7);
        GLDS(g + (size_t)row * K_DIM + c * 8, l + (size_t)(row * 8 + (j & 7)) * 8);
    }
}

// Phase template: [lgkm0; vmcnt(N); BAR; stage(region); reads; 16 MFMA].
// vmcnt ledger (2 loads per stage_X, issue order per tile: phi2 A0+B0, phi3 B1, phi4 A1;
// prologue per tile: A0,B0,B1,A1):
//   phi1 needs A0,B0 of tile t (staged at phi2(t-2)): 12 newer -> N1=12 steady
//   phi2 needs B1 (phi3(t-2)): 10 newer -> N2=10
//   phi3 needs A1 (phi4(t-2)): 12 newer (incl. this tile's phi2 stage) -> N3=12
// Tails: t=18 -> <12,10,8>, t=19 -> <4,2,0>.
template<int N1, int N2, int N3, bool STAGE>
__device__ __forceinline__ void tile_body(f16* Xa, f16* Xb,
                                          const f16* gA2, const f16* gB2,
                                          f32x4 (&acc)[8][4],
                                          int tid, int arow0, int brow0,
                                          const int (&swz)[2]) {
    f16x8 alo[4][2], ahi[4][2], blo[2][2], bhi[2][2];

    // ---- phi1: read Alo(8)+Blo(4); MFMA Q1 = Alo*Blo
    LGKM0();
    VMCNT(N1);
    BAR();
    #pragma unroll
    for (int fm = 0; fm < 4; ++fm) {
        alo[fm][0] = *(const f16x8*)&Xa[(arow0 + fm * 16) * 64 + swz[0]];
        alo[fm][1] = *(const f16x8*)&Xa[(arow0 + fm * 16) * 64 + swz[1]];
    }
    #pragma unroll
    for (int fn = 0; fn < 2; ++fn) {
        blo[fn][0] = *(const f16x8*)&Xb[(brow0 + fn * 16) * 64 + swz[0]];
        blo[fn][1] = *(const f16x8*)&Xb[(brow0 + fn * 16) * 64 + swz[1]];
    }
    __builtin_amdgcn_s_setprio(1);
    #pragma unroll
    for (int fm = 0; fm < 4; ++fm)
        #pragma unroll
        for (int fn = 0; fn < 2; ++fn) {
            acc[fm][fn] = __builtin_amdgcn_mfma_f32_16x16x32_f16(alo[fm][0], blo[fn][0], acc[fm][fn], 0, 0, 0);
            acc[fm][fn] = __builtin_amdgcn_mfma_f32_16x16x32_f16(alo[fm][1], blo[fn][1], acc[fm][fn], 0, 0, 0);
        }
    __builtin_amdgcn_s_setprio(0);

    // ---- phi2: stage A(t+2) region0 + B(t+2) region0 (read at phi1, drained); read Bhi; Q2
    LGKM0();
    VMCNT(N2);
    BAR();
    if (STAGE) { stage_A(gA2, Xa, tid, 0); stage_B(gB2, Xb, tid, 0); }
    #pragma unroll
    for (int fn = 0; fn < 2; ++fn) {
        bhi[fn][0] = *(const f16x8*)&Xb[(brow0 + 32 + fn * 16) * 64 + swz[0]];
        bhi[fn][1] = *(const f16x8*)&Xb[(brow0 + 32 + fn * 16) * 64 + swz[1]];
    }
    __builtin_amdgcn_s_setprio(1);
    #pragma unroll
    for (int fm = 0; fm < 4; ++fm)
        #pragma unroll
        for (int fn = 0; fn < 2; ++fn) {
            acc[fm][fn + 2] = __builtin_amdgcn_mfma_f32_16x16x32_f16(alo[fm][0], bhi[fn][0], acc[fm][fn + 2], 0, 0, 0);
            acc[fm][fn + 2] = __builtin_amdgcn_mfma_f32_16x16x32_f16(alo[fm][1], bhi[fn][1], acc[fm][fn + 2], 0, 0, 0);
        }
    __builtin_amdgcn_s_setprio(0);

    // ---- phi3: stage B(t+2) region1 (read at phi2, drained); read Ahi; Q3
    LGKM0();
    VMCNT(N3);
    BAR();
    if (STAGE) stage_B(gB2, Xb, tid, 1);
    #pragma unroll
    for (int fm = 0; fm < 4; ++fm) {
        ahi[fm][0] = *(const f16x8*)&Xa[(arow0 + 64 + fm * 16) * 64 + swz[0]];
        ahi[fm][1] = *(const f16x8*)&Xa[(arow0 + 64 + fm * 16) * 64 + swz[1]];
    }
    __builtin_amdgcn_s_setprio(1);
    #pragma unroll
    for (int fm = 0; fm < 4; ++fm)
        #pragma unroll
        for (int fn = 0; fn < 2; ++fn) {
            acc[fm + 4][fn + 2] = __builtin_amdgcn_mfma_f32_16x16x32_f16(ahi[fm][0], bhi[fn][0], acc[fm + 4][fn + 2], 0, 0, 0);
            acc[fm + 4][fn + 2] = __builtin_amdgcn_mfma_f32_16x16x32_f16(ahi[fm][1], bhi[fn][1], acc[fm + 4][fn + 2], 0, 0, 0);
        }
    __builtin_amdgcn_s_setprio(0);

    // ---- phi4: stage A(t+2) region1 (read at phi3, drained); MFMA Q4 = Ahi*Blo
    LGKM0();
    BAR();
    if (STAGE) stage_A(gA2, Xa, tid, 1);
    __builtin_amdgcn_s_setprio(1);
    #pragma unroll
    for (int fm = 0; fm < 4; ++fm)
        #pragma unroll
        for (int fn = 0; fn < 2; ++fn) {
            acc[fm + 4][fn] = __builtin_amdgcn_mfma_f32_16x16x32_f16(ahi[fm][0], blo[fn][0], acc[fm + 4][fn], 0, 0, 0);
            acc[fm + 4][fn] = __builtin_amdgcn_mfma_f32_16x16x32_f16(ahi[fm][1], blo[fn][1], acc[fm + 4][fn], 0, 0, 0);
        }
    __builtin_amdgcn_s_setprio(0);
}

__global__ __launch_bounds__(512, 2) void gemm_kernel(const f16* __restrict__ A,
                                                      const f16* __restrict__ B,
                                                      const float* __restrict__ bias,
                                                      float* __restrict__ C) {
    extern __shared__ f16 sm[];            // 2 bufs x (A 16384 + B 16384 f16) = 128 KiB
    int mt = blockIdx.x / NTN;
    int nt = blockIdx.x % NTN;

    int tid  = threadIdx.x;
    int lane = tid & 63;
    int wid  = tid >> 6;
    int wr   = wid >> 2;                   // 0..1
    int wc   = wid & 3;                    // 0..3
    int l15  = lane & 15;

    int swz[2] = { (((lane >> 4)    ) ^ (lane & 7)) * 8,
                   (((lane >> 4) + 4) ^ (lane & 7)) * 8 };
    int arow0 = wr * 128 + l15;
    int brow0 = wc * 64 + l15;

    const f16* gAb = A + (size_t)(mt * 256) * K_DIM;
    const f16* gBb = B + (size_t)(nt * 256) * K_DIM;

    f16* A0 = sm;
    f16* B0 = sm + 16384;
    f16* A1 = sm + 32768;
    f16* B1 = sm + 49152;

    f32x4 acc[8][4] = {};

    // prologue: stage tiles 0,1 in ledger order {A.r0, B.r0, B.r1, A.r1} per tile.
    stage_A(gAb,      A0, tid, 0);
    stage_B(gBb,      B0, tid, 0);
    stage_B(gBb,      B0, tid, 1);
    stage_A(gAb,      A0, tid, 1);
    stage_A(gAb + 64, A1, tid, 0);
    stage_B(gBb + 64, B1, tid, 0);
    stage_B(gBb + 64, B1, tid, 1);
    stage_A(gAb + 64, A1, tid, 1);

    for (int tt = 0; tt < 9; ++tt) {
        int t0 = 2 * tt;
        tile_body<12, 10, 12, true>(A0, B0, gAb + (t0 + 2) * 64, gBb + (t0 + 2) * 64,
                                    acc, tid, arow0, brow0, swz);
        tile_body<12, 10, 12, true>(A1, B1, gAb + (t0 + 3) * 64, gBb + (t0 + 3) * 64,
                                    acc, tid, arow0, brow0, swz);
    }
    tile_body<12, 10, 8, false>(A0, B0, gAb, gBb, acc, tid, arow0, brow0, swz);  // t=18
    tile_body<4, 2, 0, false>(A1, B1, gAb, gBb, acc, tid, arow0, brow0, swz);    // t=19

    // ---- epilogue: C = acc + bias.  C/D layout: col=lane&15, row=(lane>>4)*4+j
    int crow0 = mt * 256 + wr * 128;
    int ccol  = nt * 256 + wc * 64 + l15;
    float bz[4];
    #pragma unroll
    for (int fn = 0; fn < 4; ++fn) bz[fn] = bias[ccol + fn * 16];

    #pragma unroll
    for (int fm = 0; fm < 8; ++fm) {
        #pragma unroll
        for (int j = 0; j < 4; ++j) {
            int row = crow0 + fm * 16 + (lane >> 4) * 4 + j;
            if (row < M_ROWS) {
                float* cp = C + (size_t)row * N_COLS + ccol;
                #pragma unroll
                for (int fn = 0; fn < 4; ++fn)
                    cp[fn * 16] = acc[fm][fn][j] + bz[fn];
            }
        }
    }
}

extern "C" void kernel_launch(void* const* d_in, const int* in_sizes, int n_in,
                              void* d_out, int out_size, void* d_ws, size_t ws_size,
                              hipStream_t stream) {
    const float* x      = (const float*)d_in[0];
    const float* weight = (const float*)d_in[1];
    const float* bias   = (const float*)d_in[2];
    float* out     = (float*)d_out;
    float* scale_w = (float*)d_out + (size_t)M_ROWS * N_COLS;

    f16* xq = (f16*)d_ws;
    f16* wq = (f16*)((char*)d_ws + (size_t)M_PAD * K_DIM * sizeof(f16));

    (void)hipFuncSetAttribute((const void*)gemm_kernel,
                              hipFuncAttributeMaxDynamicSharedMemorySize, 131072);

    {
        int threads = M_PAD * (K_DIM / 8);
        quant_x_kernel<<<threads / 256, 256, 0, stream>>>(x, xq);
    }
    {
        int threads = N_COLS * (K_DIM / 8);
        quant_w_kernel<<<threads / 256, 256, 0, stream>>>(weight, wq, scale_w);
    }
    {
        int grid = (M_PAD / 256) * (N_COLS / 256);   // 47 * 20 = 940
        gemm_kernel<<<grid, 512, 131072, stream>>>(xq, wq, bias, out);
    }
}

// Round 7
// 218.199 us; speedup vs baseline: 1.1386x; 1.1386x over previous
//
#include <hip/hip_runtime.h>
#include <hip/hip_fp16.h>

// QuantizedLinearWhisper: E2M1 block-32 fake-quant of x and W, then x_q @ W_q^T + bias.
// M=12000 (pad 12032=94*128), K=1280, N=5120. Outputs: out[12000][5120] f32, scale_w[5120][40] f32.
//
// R7: occupancy-driven overlap. 128x256 tile, BK=32, 512 threads (8 waves 2x4, wave
// tile 64x64), acc=64 regs -> <=128 unified VGPR -> 4 waves/SIMD -> 2 blocks/CU.
// Two co-resident blocks anti-phase so one block's MFMA overlaps the other's LDS
// traffic (m114) -- no barrier heroics needed. 2 phases/K-tile, spread staging
// (Bhi(t+1) at phi1, A+Blo(t+2) at phi2), counted vmcnt(2), 2-bit XOR chunk swizzle.

typedef _Float16 f16;
typedef _Float16 f16x8 __attribute__((ext_vector_type(8)));
typedef float f32x4 __attribute__((ext_vector_type(4)));

#define M_ROWS 12000
#define M_PAD  12032
#define N_COLS 5120
#define K_DIM  1280
#define KB     40
#define NT     40          // K tiles of 32
#define NTN    20          // N tiles of 256

#define BAR()   asm volatile("s_barrier" ::: "memory")
#define LGKM0() asm volatile("s_waitcnt lgkmcnt(0)" ::: "memory")
#define VMCNT(N) asm volatile("s_waitcnt vmcnt(%0)" :: "i"(N) : "memory")
#define GLDS(gp, lp) __builtin_amdgcn_global_load_lds( \
    (const __attribute__((address_space(1))) unsigned*)(gp), \
    (__attribute__((address_space(3))) unsigned*)(lp), 16, 0, 0)

// ---- E2M1 nearest-level (strict > boundaries, identical to reference) ----
__device__ __forceinline__ float e2m1_level(float a) {
    float lv;
    if (a > 2.5f)       lv = (a > 3.5f) ? ((a > 5.0f) ? 6.0f : 4.0f) : 3.0f;
    else if (a > 1.25f) lv = (a > 1.75f) ? 2.0f : 1.5f;
    else                lv = (a > 0.75f) ? 1.0f : ((a > 0.25f) ? 0.5f : 0.0f);
    return lv;
}

__global__ __launch_bounds__(256) void quant_x_kernel(const float* __restrict__ x,
                                                      f16* __restrict__ xq) {
    int t = blockIdx.x * blockDim.x + threadIdx.x;
    int row = t / 160;
    int c8  = t % 160;
    f16x8 o;
    if (row < M_ROWS) {
        const float* p = x + (size_t)row * K_DIM + c8 * 8;
        float v[8];
        *(float4*)&v[0] = *(const float4*)p;
        *(float4*)&v[4] = *(const float4*)(p + 4);
        float am = 0.0f;
        #pragma unroll
        for (int i = 0; i < 8; ++i) am = fmaxf(am, fabsf(v[i]));
        am = fmaxf(am, __shfl_xor(am, 1));
        am = fmaxf(am, __shfl_xor(am, 2));
        float scale = fmaxf(am / 6.0f, 1e-12f);
        #pragma unroll
        for (int i = 0; i < 8; ++i) {
            float tq = v[i] / scale;
            float q  = copysignf(e2m1_level(fabsf(tq)), tq) * scale;
            o[i] = (f16)q;
        }
    } else {
        #pragma unroll
        for (int i = 0; i < 8; ++i) o[i] = (f16)0.0f;
    }
    *(f16x8*)(xq + (size_t)row * K_DIM + c8 * 8) = o;
}

__global__ __launch_bounds__(256) void quant_w_kernel(const float* __restrict__ w,
                                                      f16* __restrict__ wq,
                                                      float* __restrict__ scale_out) {
    int t = blockIdx.x * blockDim.x + threadIdx.x;
    int row = t / 160;
    int c8  = t % 160;
    const float* p = w + (size_t)row * K_DIM + c8 * 8;
    float v[8];
    *(float4*)&v[0] = *(const float4*)p;
    *(float4*)&v[4] = *(const float4*)(p + 4);
    float am = 0.0f;
    #pragma unroll
    for (int i = 0; i < 8; ++i) am = fmaxf(am, fabsf(v[i]));
    am = fmaxf(am, __shfl_xor(am, 1));
    am = fmaxf(am, __shfl_xor(am, 2));
    float scale = fmaxf(am / 6.0f, 1e-12f);
    if ((t & 3) == 0) scale_out[row * KB + (c8 >> 2)] = scale;
    f16x8 o;
    #pragma unroll
    for (int i = 0; i < 8; ++i) {
        float tq = v[i] / scale;
        float q  = copysignf(e2m1_level(fabsf(tq)), tq) * scale;
        o[i] = (f16)q;
    }
    *(f16x8*)(wq + (size_t)row * K_DIM + c8 * 8) = o;
}

// ---- GEMM 128x256, BK=32 ----
// LDS buffers (f16): A [128 rows][4 chunks of 16B] = 4096, B [256][4] = 8192.
// Chunk c of row r stored at slot (c ^ (r&3)); staging pre-swizzles the global source.

// A tile: 512 chunks, 1 load/thread; dst linear = tid*16B.
__device__ __forceinline__ void stage_A32(const f16* __restrict__ g, f16* l, int tid) {
    int r = tid >> 2;
    int c = (tid & 3) ^ (r & 3);
    GLDS(g + (size_t)r * K_DIM + c * 8, l + (size_t)tid * 8);
}
// B half h: rows {r: (r>>5)&1 == h}, 128 rows = 512 chunks, 1 load/thread.
__device__ __forceinline__ void stage_B32(const f16* __restrict__ g, f16* l, int tid, int h) {
    int rr  = tid >> 2;
    int row = (rr & 31) + ((rr >> 5) << 6) + (h << 5);
    int c   = (tid & 3) ^ (row & 3);
    GLDS(g + (size_t)row * K_DIM + c * 8, l + (size_t)(row * 4 + (tid & 3)) * 8);
}

// One K-tile (K=32). Ab/Bb = current buffers; oBb = other B buffer (Bhi(t+1) target).
// phi1: [lgkm0; vmcnt(VM); BAR] stage Bhi(t+1); read a(4)+blo(2); 8 MFMA (fn 0-1)
// phi2: [lgkm0; BAR] stage A(t+2)+Blo(t+2); read bhi(2); 8 MFMA (fn 2-3)
template<int VM, bool S1, bool S2>
__device__ __forceinline__ void ktile(const f16* Ab, const f16* Bb, f16* oBb,
                                      f16* Ab_w, f16* Bb_w,
                                      const f16* gA2, const f16* gB2, const f16* gB1,
                                      f32x4 (&acc)[4][4],
                                      int tid, int arow0, int brow0, int swzc) {
    f16x8 a[4], bl[2], bh[2];

    LGKM0();               // prior-phase reads of oBb's hi region drained (stage safety)
    VMCNT(VM);             // tile t fully staged (ledger: 2 newer loads allowed)
    BAR();
    if (S1) stage_B32(gB1, oBb, tid, 1);        // Bhi(t+1) -> other buffer
    #pragma unroll
    for (int fm = 0; fm < 4; ++fm)
        a[fm] = *(const f16x8*)&Ab[(arow0 + fm * 16) * 32 + swzc];
    #pragma unroll
    for (int fn = 0; fn < 2; ++fn)
        bl[fn] = *(const f16x8*)&Bb[(brow0 + fn * 16) * 32 + swzc];
    __builtin_amdgcn_s_setprio(1);
    #pragma unroll
    for (int fm = 0; fm < 4; ++fm)
        #pragma unroll
        for (int fn = 0; fn < 2; ++fn)
            acc[fm][fn] = __builtin_amdgcn_mfma_f32_16x16x32_f16(a[fm], bl[fn], acc[fm][fn], 0, 0, 0);
    __builtin_amdgcn_s_setprio(0);

    LGKM0();               // a/blo reads of this buffer drained (stage safety)
    BAR();
    if (S2) { stage_A32(gA2, Ab_w, tid); stage_B32(gB2, Bb_w, tid, 0); }
    #pragma unroll
    for (int fn = 0; fn < 2; ++fn)
        bh[fn] = *(const f16x8*)&Bb[(brow0 + 32 + fn * 16) * 32 + swzc];
    __builtin_amdgcn_s_setprio(1);
    #pragma unroll
    for (int fm = 0; fm < 4; ++fm)
        #pragma unroll
        for (int fn = 0; fn < 2; ++fn)
            acc[fm][fn + 2] = __builtin_amdgcn_mfma_f32_16x16x32_f16(a[fm], bh[fn], acc[fm][fn + 2], 0, 0, 0);
    __builtin_amdgcn_s_setprio(0);
}

__global__ __launch_bounds__(512, 4) void gemm_kernel(const f16* __restrict__ A,
                                                      const f16* __restrict__ B,
                                                      const float* __restrict__ bias,
                                                      float* __restrict__ C) {
    __shared__ f16 sm[24576];              // 48 KiB: A0 B0 A1 B1
    f16* A0 = sm;
    f16* B0 = sm + 4096;
    f16* A1 = sm + 12288;
    f16* B1 = sm + 16384;

    int mt = blockIdx.x / NTN;             // 94 m-tiles of 128
    int nt = blockIdx.x % NTN;             // 20 n-tiles of 256

    int tid  = threadIdx.x;
    int lane = tid & 63;
    int wid  = tid >> 6;
    int wr   = wid >> 2;                   // 0..1  (M)
    int wc   = wid & 3;                    // 0..3  (N)
    int l15  = lane & 15;

    int swzc  = (((lane >> 4) ^ (l15 & 3)) << 3);   // swizzled chunk offset (f16)
    int arow0 = wr * 64 + l15;
    int brow0 = wc * 64 + l15;

    const f16* gAb = A + (size_t)(mt * 128) * K_DIM;
    const f16* gBb = B + (size_t)(nt * 256) * K_DIM;

    f32x4 acc[4][4] = {};

    // prologue, ledger order: A0,BL0,BH0, A1,BL1  (BH1 staged at phi1 of tile 0)
    stage_A32(gAb,      A0, tid);
    stage_B32(gBb,      B0, tid, 0);
    stage_B32(gBb,      B0, tid, 1);
    stage_A32(gAb + 32, A1, tid);
    stage_B32(gBb + 32, B1, tid, 0);

    // main: tiles 0..37 staged; 38 stages only Bhi(39); 39 stages nothing.
    for (int tt = 0; tt < 19; ++tt) {
        int t = 2 * tt;
        ktile<2, true, true>(A0, B0, B1, A0, B0,
                             gAb + (t + 2) * 32, gBb + (t + 2) * 32, gBb + (t + 1) * 32,
                             acc, tid, arow0, brow0, swzc);
        ktile<2, true, true>(A1, B1, B0, A1, B1,
                             gAb + (t + 3) * 32, gBb + (t + 3) * 32, gBb + (t + 2) * 32,
                             acc, tid, arow0, brow0, swzc);
    }
    ktile<2, true, false>(A0, B0, B1, A0, B0, gAb, gBb, gBb + 39 * 32,
                          acc, tid, arow0, brow0, swzc);   // t=38
    ktile<0, false, false>(A1, B1, B0, A1, B1, gAb, gBb, gBb,
                           acc, tid, arow0, brow0, swzc);  // t=39

    // ---- epilogue: C = acc + bias.  C/D layout: col=lane&15, row=(lane>>4)*4+j
    int crow0 = mt * 128 + wr * 64;
    int ccol  = nt * 256 + wc * 64 + l15;
    float bz[4];
    #pragma unroll
    for (int fn = 0; fn < 4; ++fn) bz[fn] = bias[ccol + fn * 16];

    #pragma unroll
    for (int fm = 0; fm < 4; ++fm) {
        #pragma unroll
        for (int j = 0; j < 4; ++j) {
            int row = crow0 + fm * 16 + (lane >> 4) * 4 + j;
            if (row < M_ROWS) {
                float* cp = C + (size_t)row * N_COLS + ccol;
                #pragma unroll
                for (int fn = 0; fn < 4; ++fn)
                    cp[fn * 16] = acc[fm][fn][j] + bz[fn];
            }
        }
    }
}

extern "C" void kernel_launch(void* const* d_in, const int* in_sizes, int n_in,
                              void* d_out, int out_size, void* d_ws, size_t ws_size,
                              hipStream_t stream) {
    const float* x      = (const float*)d_in[0];
    const float* weight = (const float*)d_in[1];
    const float* bias   = (const float*)d_in[2];
    float* out     = (float*)d_out;
    float* scale_w = (float*)d_out + (size_t)M_ROWS * N_COLS;

    f16* xq = (f16*)d_ws;
    f16* wq = (f16*)((char*)d_ws + (size_t)M_PAD * K_DIM * sizeof(f16));

    {
        int threads = M_PAD * (K_DIM / 8);
        quant_x_kernel<<<threads / 256, 256, 0, stream>>>(x, xq);
    }
    {
        int threads = N_COLS * (K_DIM / 8);
        quant_w_kernel<<<threads / 256, 256, 0, stream>>>(weight, wq, scale_w);
    }
    {
        int grid = (M_PAD / 128) * (N_COLS / 256);   // 94 * 20 = 1880
        gemm_kernel<<<grid, 512, 0, stream>>>(xq, wq, bias, out);
    }
}

// Round 8
// 215.981 us; speedup vs baseline: 1.1503x; 1.0103x over previous
//
#include <hip/hip_runtime.h>
#include <hip/hip_fp16.h>

// QuantizedLinearWhisper: E2M1 block-32 fake-quant of x and W, then x_q @ W_q^T + bias.
// M=12000 (pad 12032=94*128), K=1280, N=5120. Outputs: out[12000][5120] f32, scale_w[5120][40] f32.
//
// R8 = R7 (occupancy-overlap design: 128x256 tile, BK=32, 8 waves 2x4, wave tile 64x64,
// VGPR<=128 unified -> 2 blocks/CU; 2 phases/K-tile, spread staging, counted vmcnt(2))
// + FIXED LDS swizzle for 64B rows: f(row) = (row>>1)&3 (was row&3, which left 4-way
// quarter-wave conflicts -> 1.9e7 conflict cycles). slot(l15)=16*(l15&1)+4*(g^((l15>>1)&3))
// covers all 8 16B-slots with exactly 2 lanes each -> conflict-free.

typedef _Float16 f16;
typedef _Float16 f16x8 __attribute__((ext_vector_type(8)));
typedef float f32x4 __attribute__((ext_vector_type(4)));

#define M_ROWS 12000
#define M_PAD  12032
#define N_COLS 5120
#define K_DIM  1280
#define KB     40
#define NT     40          // K tiles of 32
#define NTN    20          // N tiles of 256

#define BAR()   asm volatile("s_barrier" ::: "memory")
#define LGKM0() asm volatile("s_waitcnt lgkmcnt(0)" ::: "memory")
#define VMCNT(N) asm volatile("s_waitcnt vmcnt(%0)" :: "i"(N) : "memory")
#define GLDS(gp, lp) __builtin_amdgcn_global_load_lds( \
    (const __attribute__((address_space(1))) unsigned*)(gp), \
    (__attribute__((address_space(3))) unsigned*)(lp), 16, 0, 0)

// ---- E2M1 nearest-level (strict > boundaries, identical to reference) ----
__device__ __forceinline__ float e2m1_level(float a) {
    float lv;
    if (a > 2.5f)       lv = (a > 3.5f) ? ((a > 5.0f) ? 6.0f : 4.0f) : 3.0f;
    else if (a > 1.25f) lv = (a > 1.75f) ? 2.0f : 1.5f;
    else                lv = (a > 0.75f) ? 1.0f : ((a > 0.25f) ? 0.5f : 0.0f);
    return lv;
}

__global__ __launch_bounds__(256) void quant_x_kernel(const float* __restrict__ x,
                                                      f16* __restrict__ xq) {
    int t = blockIdx.x * blockDim.x + threadIdx.x;
    int row = t / 160;
    int c8  = t % 160;
    f16x8 o;
    if (row < M_ROWS) {
        const float* p = x + (size_t)row * K_DIM + c8 * 8;
        float v[8];
        *(float4*)&v[0] = *(const float4*)p;
        *(float4*)&v[4] = *(const float4*)(p + 4);
        float am = 0.0f;
        #pragma unroll
        for (int i = 0; i < 8; ++i) am = fmaxf(am, fabsf(v[i]));
        am = fmaxf(am, __shfl_xor(am, 1));
        am = fmaxf(am, __shfl_xor(am, 2));
        float scale = fmaxf(am / 6.0f, 1e-12f);
        #pragma unroll
        for (int i = 0; i < 8; ++i) {
            float tq = v[i] / scale;
            float q  = copysignf(e2m1_level(fabsf(tq)), tq) * scale;
            o[i] = (f16)q;
        }
    } else {
        #pragma unroll
        for (int i = 0; i < 8; ++i) o[i] = (f16)0.0f;
    }
    *(f16x8*)(xq + (size_t)row * K_DIM + c8 * 8) = o;
}

__global__ __launch_bounds__(256) void quant_w_kernel(const float* __restrict__ w,
                                                      f16* __restrict__ wq,
                                                      float* __restrict__ scale_out) {
    int t = blockIdx.x * blockDim.x + threadIdx.x;
    int row = t / 160;
    int c8  = t % 160;
    const float* p = w + (size_t)row * K_DIM + c8 * 8;
    float v[8];
    *(float4*)&v[0] = *(const float4*)p;
    *(float4*)&v[4] = *(const float4*)(p + 4);
    float am = 0.0f;
    #pragma unroll
    for (int i = 0; i < 8; ++i) am = fmaxf(am, fabsf(v[i]));
    am = fmaxf(am, __shfl_xor(am, 1));
    am = fmaxf(am, __shfl_xor(am, 2));
    float scale = fmaxf(am / 6.0f, 1e-12f);
    if ((t & 3) == 0) scale_out[row * KB + (c8 >> 2)] = scale;
    f16x8 o;
    #pragma unroll
    for (int i = 0; i < 8; ++i) {
        float tq = v[i] / scale;
        float q  = copysignf(e2m1_level(fabsf(tq)), tq) * scale;
        o[i] = (f16)q;
    }
    *(f16x8*)(wq + (size_t)row * K_DIM + c8 * 8) = o;
}

// ---- GEMM 128x256, BK=32 ----
// LDS buffers (f16): A [128 rows][4 chunks of 16B] = 4096, B [256][4] = 8192.
// Chunk c of row r stored at slot (c ^ ((r>>1)&3)); staging pre-swizzles the source.

__device__ __forceinline__ void stage_A32(const f16* __restrict__ g, f16* l, int tid) {
    int r = tid >> 2;
    int c = (tid & 3) ^ ((r >> 1) & 3);
    GLDS(g + (size_t)r * K_DIM + c * 8, l + (size_t)tid * 8);
}
// B half h: rows {r: (r>>5)&1 == h}, 128 rows = 512 chunks, 1 load/thread.
__device__ __forceinline__ void stage_B32(const f16* __restrict__ g, f16* l, int tid, int h) {
    int rr  = tid >> 2;
    int row = (rr & 31) + ((rr >> 5) << 6) + (h << 5);
    int c   = (tid & 3) ^ ((row >> 1) & 3);
    GLDS(g + (size_t)row * K_DIM + c * 8, l + (size_t)(row * 4 + (tid & 3)) * 8);
}

// One K-tile (K=32). Ab/Bb = current buffers; oBb = other B buffer (Bhi(t+1) target).
// phi1: [lgkm0; vmcnt(VM); BAR] stage Bhi(t+1); read a(4)+blo(2); 8 MFMA (fn 0-1)
// phi2: [lgkm0; BAR] stage A(t+2)+Blo(t+2); read bhi(2); 8 MFMA (fn 2-3)
template<int VM, bool S1, bool S2>
__device__ __forceinline__ void ktile(const f16* Ab, const f16* Bb, f16* oBb,
                                      f16* Ab_w, f16* Bb_w,
                                      const f16* gA2, const f16* gB2, const f16* gB1,
                                      f32x4 (&acc)[4][4],
                                      int tid, int arow0, int brow0, int swzc) {
    f16x8 a[4], bl[2], bh[2];

    LGKM0();               // prior-phase reads of oBb's hi region drained (stage safety)
    VMCNT(VM);             // tile t fully staged (ledger: 2 newer loads allowed)
    BAR();
    if (S1) stage_B32(gB1, oBb, tid, 1);        // Bhi(t+1) -> other buffer
    #pragma unroll
    for (int fm = 0; fm < 4; ++fm)
        a[fm] = *(const f16x8*)&Ab[(arow0 + fm * 16) * 32 + swzc];
    #pragma unroll
    for (int fn = 0; fn < 2; ++fn)
        bl[fn] = *(const f16x8*)&Bb[(brow0 + fn * 16) * 32 + swzc];
    __builtin_amdgcn_s_setprio(1);
    #pragma unroll
    for (int fm = 0; fm < 4; ++fm)
        #pragma unroll
        for (int fn = 0; fn < 2; ++fn)
            acc[fm][fn] = __builtin_amdgcn_mfma_f32_16x16x32_f16(a[fm], bl[fn], acc[fm][fn], 0, 0, 0);
    __builtin_amdgcn_s_setprio(0);

    LGKM0();               // a/blo reads of this buffer drained (stage safety)
    BAR();
    if (S2) { stage_A32(gA2, Ab_w, tid); stage_B32(gB2, Bb_w, tid, 0); }
    #pragma unroll
    for (int fn = 0; fn < 2; ++fn)
        bh[fn] = *(const f16x8*)&Bb[(brow0 + 32 + fn * 16) * 32 + swzc];
    __builtin_amdgcn_s_setprio(1);
    #pragma unroll
    for (int fm = 0; fm < 4; ++fm)
        #pragma unroll
        for (int fn = 0; fn < 2; ++fn)
            acc[fm][fn + 2] = __builtin_amdgcn_mfma_f32_16x16x32_f16(a[fm], bh[fn], acc[fm][fn + 2], 0, 0, 0);
    __builtin_amdgcn_s_setprio(0);
}

__global__ __launch_bounds__(512, 4) void gemm_kernel(const f16* __restrict__ A,
                                                      const f16* __restrict__ B,
                                                      const float* __restrict__ bias,
                                                      float* __restrict__ C) {
    __shared__ f16 sm[24576];              // 48 KiB: A0 B0 A1 B1
    f16* A0 = sm;
    f16* B0 = sm + 4096;
    f16* A1 = sm + 12288;
    f16* B1 = sm + 16384;

    int mt = blockIdx.x / NTN;             // 94 m-tiles of 128
    int nt = blockIdx.x % NTN;             // 20 n-tiles of 256

    int tid  = threadIdx.x;
    int lane = tid & 63;
    int wid  = tid >> 6;
    int wr   = wid >> 2;                   // 0..1  (M)
    int wc   = wid & 3;                    // 0..3  (N)
    int l15  = lane & 15;

    // swizzled chunk offset: g ^ ((row>>1)&3); row low bits == l15 for all frags
    int swzc  = (((lane >> 4) ^ ((l15 >> 1) & 3)) << 3);
    int arow0 = wr * 64 + l15;
    int brow0 = wc * 64 + l15;

    const f16* gAb = A + (size_t)(mt * 128) * K_DIM;
    const f16* gBb = B + (size_t)(nt * 256) * K_DIM;

    f32x4 acc[4][4] = {};

    // prologue, ledger order: A0,BL0,BH0, A1,BL1  (BH1 staged at phi1 of tile 0)
    stage_A32(gAb,      A0, tid);
    stage_B32(gBb,      B0, tid, 0);
    stage_B32(gBb,      B0, tid, 1);
    stage_A32(gAb + 32, A1, tid);
    stage_B32(gBb + 32, B1, tid, 0);

    // main: tiles 0..37 staged; 38 stages only Bhi(39); 39 stages nothing.
    for (int tt = 0; tt < 19; ++tt) {
        int t = 2 * tt;
        ktile<2, true, true>(A0, B0, B1, A0, B0,
                             gAb + (t + 2) * 32, gBb + (t + 2) * 32, gBb + (t + 1) * 32,
                             acc, tid, arow0, brow0, swzc);
        ktile<2, true, true>(A1, B1, B0, A1, B1,
                             gAb + (t + 3) * 32, gBb + (t + 3) * 32, gBb + (t + 2) * 32,
                             acc, tid, arow0, brow0, swzc);
    }
    ktile<2, true, false>(A0, B0, B1, A0, B0, gAb, gBb, gBb + 39 * 32,
                          acc, tid, arow0, brow0, swzc);   // t=38
    ktile<0, false, false>(A1, B1, B0, A1, B1, gAb, gBb, gBb,
                           acc, tid, arow0, brow0, swzc);  // t=39

    // ---- epilogue: C = acc + bias.  C/D layout: col=lane&15, row=(lane>>4)*4+j
    int crow0 = mt * 128 + wr * 64;
    int ccol  = nt * 256 + wc * 64 + l15;
    float bz[4];
    #pragma unroll
    for (int fn = 0; fn < 4; ++fn) bz[fn] = bias[ccol + fn * 16];

    #pragma unroll
    for (int fm = 0; fm < 4; ++fm) {
        #pragma unroll
        for (int j = 0; j < 4; ++j) {
            int row = crow0 + fm * 16 + (lane >> 4) * 4 + j;
            if (row < M_ROWS) {
                float* cp = C + (size_t)row * N_COLS + ccol;
                #pragma unroll
                for (int fn = 0; fn < 4; ++fn)
                    cp[fn * 16] = acc[fm][fn][j] + bz[fn];
            }
        }
    }
}

extern "C" void kernel_launch(void* const* d_in, const int* in_sizes, int n_in,
                              void* d_out, int out_size, void* d_ws, size_t ws_size,
                              hipStream_t stream) {
    const float* x      = (const float*)d_in[0];
    const float* weight = (const float*)d_in[1];
    const float* bias   = (const float*)d_in[2];
    float* out     = (float*)d_out;
    float* scale_w = (float*)d_out + (size_t)M_ROWS * N_COLS;

    f16* xq = (f16*)d_ws;
    f16* wq = (f16*)((char*)d_ws + (size_t)M_PAD * K_DIM * sizeof(f16));

    {
        int threads = M_PAD * (K_DIM / 8);
        quant_x_kernel<<<threads / 256, 256, 0, stream>>>(x, xq);
    }
    {
        int threads = N_COLS * (K_DIM / 8);
        quant_w_kernel<<<threads / 256, 256, 0, stream>>>(weight, wq, scale_w);
    }
    {
        int grid = (M_PAD / 128) * (N_COLS / 256);   // 94 * 20 = 1880
        gemm_kernel<<<grid, 512, 0, stream>>>(xq, wq, bias, out);
    }
}